// Round 1
// baseline (998.061 us; speedup 1.0000x reference)
//
#include <hip/hip_runtime.h>

#define SEQ   2048
#define BATCH 256
#define INDIM 64
#define HID   128

struct F2 { float x, y; };

// Permuted value via DPP. CTRL: 0xB1 quad_perm xor1, 0x4E quad_perm xor2,
// 0x124 row_ror:4, 0x128 row_ror:8.
template <int CTRL>
__device__ __forceinline__ float dpp_get(float v) {
    int t = __builtin_amdgcn_update_dpp(0, __builtin_bit_cast(int, v),
                                        CTRL, 0xF, 0xF, true);
    return __builtin_bit_cast(float, t);
}

// Packed fp32 math (VOP3P): 2 FMAs/lane/inst.
#define PK_MUL(d, a, b) asm("v_pk_mul_f32 %0, %1, %2"     : "=v"(d) : "v"(a), "v"(b))
#define PK_FMA(d, a, b) asm("v_pk_fma_f32 %0, %1, %2, %0" : "+v"(d) : "v"(a), "v"(b))

// tanh(d + bias) with bias pre-folded: m = d*K + bias*K, K = -2/ln2;
// e = 2^m = e^{-2(d+bias)}; tanh = (1-e)/(1+e).
#define TANH_K (-2.885390081777927f)
__device__ __forceinline__ float tanh_pre(float d, float bias_k) {
    float m = __builtin_fmaf(d, TANH_K, bias_k);
    float e = __builtin_amdgcn_exp2f(m);
    return (1.0f - e) * __builtin_amdgcn_rcpf(1.0f + e);
}

// R11: two independent batch chains per block (1024 thr, 16 waves, grid=128).
// Waves 0-7 = chain 0, waves 8-15 = chain 1 -> each SIMD hosts 2 waves of
// each chain; chain A's LDS-roundtrip/reduce/tanh stalls are filled by
// chain B's MAC issue. Inner per-wave math identical to the 605us kernel.
__global__ __launch_bounds__(1024)
__attribute__((amdgpu_waves_per_eu(4, 4)))   // 16 waves resident = 4/SIMD
void rnn_fused(
    const float* __restrict__ x,    // (S,B,IN)
    const float* __restrict__ Wx,   // (H,IN)
    const float* __restrict__ bx,   // (H)
    const float* __restrict__ Wh,   // (H,H)
    const float* __restrict__ bh,   // (H)
    float* __restrict__ out)        // (S,B,H) then (1,B,H)
{
    const int tid   = threadIdx.x;   // 0..1023
    const int wglob = tid >> 6;      // 0..15
    const int chain = wglob >> 3;    // 0: waves 0-7, 1: waves 8-15
    const int w     = wglob & 7;     // wave-in-chain 0..7
    const int b     = blockIdx.x * 2 + chain;
    const int l     = tid & 63;
    const int s     = l & 15;        // k-slice: h[4s..4s+3], h[64+4s..+3], x[4s..+3]
    const int j0    = w * 16 + (l >> 4) * 4;   // group base: outputs j0..j0+3

    __shared__ __align__(16) float hbuf[2][2][HID];   // [chain][bank][h]

    // ---- weights as packed float-pairs, SLOT-PERMUTED: accumulator slot o
    // holds output j0 + (o ^ (l&3)) -> cndmask-free butterfly (unchanged).
    const double* WhD = (const double*)Wh;   // 64 doubles per row
    const double* WxD = (const double*)Wx;   // 32 doubles per row
    double wA[4], wB[4], wC[4], wD[4], wX[4], wY[4];
#pragma unroll
    for (int o = 0; o < 4; ++o) {
        const int row = j0 + (o ^ (l & 3));        // slot-permuted output row
        const int r   = row * 64 + 2 * s;
        wA[o] = WhD[r];      wB[o] = WhD[r + 1];
        wC[o] = WhD[r + 32]; wD[o] = WhD[r + 33];
        const int rx  = row * 32 + 2 * s;
        wX[o] = WxD[rx];     wY[o] = WxD[rx + 1];
    }
    const int jj = j0 + (l & 3);          // output this lane holds after reduce
    float bias_k = (bx[jj] + bh[jj]) * TANH_K;   // pre-folded into exp arg

    if (tid < 512) ((float*)hbuf)[tid] = 0.0f;   // zero both chains' banks
    __syncthreads();

    // x in registers: per-thread double2 (=float4) slice, 4-step banks,
    // double-buffered. Compiler-placed vmcnt waits land at bank rotation.
    const double2* xb2 = (const double2*)(x + (size_t)b * INDIM + 4 * s);
    const size_t   S2  = (size_t)BATCH * INDIM / 4;   // double2 per timestep
    double2 xa[4], xn[4];
#pragma unroll
    for (int i = 0; i < 4; ++i) xa[i] = xb2[(size_t)i * S2];

    float* outp = out + (size_t)b * HID + jj;  // running pointer
    const bool wr = (s < 4);                   // 16 lanes/wave write
    float hv = 0.0f;

    for (int tb = 0; tb < SEQ; tb += 4) {
        // In-loop pin (once per 4 steps): loop-carried "+v" keeps weights
        // VGPR-resident — no AGPR parking, no remat.
        asm volatile("" : "+v"(wA[0]), "+v"(wA[1]), "+v"(wA[2]), "+v"(wA[3]));
        asm volatile("" : "+v"(wB[0]), "+v"(wB[1]), "+v"(wB[2]), "+v"(wB[3]));
        asm volatile("" : "+v"(wC[0]), "+v"(wC[1]), "+v"(wC[2]), "+v"(wC[3]));
        asm volatile("" : "+v"(wD[0]), "+v"(wD[1]), "+v"(wD[2]), "+v"(wD[3]));
        asm volatile("" : "+v"(wX[0]), "+v"(wX[1]), "+v"(wX[2]), "+v"(wX[3]));
        asm volatile("" : "+v"(wY[0]), "+v"(wY[1]), "+v"(wY[2]), "+v"(wY[3]));
        asm volatile("" : "+v"(bias_k));

        // issue next bank (steps tb+4..tb+7, clamped at the tail)
#pragma unroll
        for (int i = 0; i < 4; ++i) {
            int tp = tb + 4 + i; if (tp > SEQ - 1) tp = SEQ - 1;
            xn[i] = xb2[(size_t)tp * S2];
        }

#pragma unroll
        for (int q = 0; q < 4; ++q) {
            const double2* hbd = (const double2*)&hbuf[chain][q & 1][0];

            // 2 ds_read_b128: granules s and 16+s, 4-way g-broadcast — conflict-free
            const double2 H0 = hbd[s];
            const double2 H1 = hbd[16 + s];
            const double2 X  = xa[q];

            double acc0, acc1, acc2, acc3;
            // x first: independent of h -> schedules into ds_read shadow
            PK_MUL(acc0, X.x, wX[0]); PK_MUL(acc1, X.x, wX[1]);
            PK_MUL(acc2, X.x, wX[2]); PK_MUL(acc3, X.x, wX[3]);
            PK_FMA(acc0, X.y, wY[0]); PK_FMA(acc1, X.y, wY[1]);
            PK_FMA(acc2, X.y, wY[2]); PK_FMA(acc3, X.y, wY[3]);
            PK_FMA(acc0, H0.x, wA[0]); PK_FMA(acc1, H0.x, wA[1]);
            PK_FMA(acc2, H0.x, wA[2]); PK_FMA(acc3, H0.x, wA[3]);
            PK_FMA(acc0, H0.y, wB[0]); PK_FMA(acc1, H0.y, wB[1]);
            PK_FMA(acc2, H0.y, wB[2]); PK_FMA(acc3, H0.y, wB[3]);
            PK_FMA(acc0, H1.x, wC[0]); PK_FMA(acc1, H1.x, wC[1]);
            PK_FMA(acc2, H1.x, wC[2]); PK_FMA(acc3, H1.x, wC[3]);
            PK_FMA(acc0, H1.y, wD[0]); PK_FMA(acc1, H1.y, wD[1]);
            PK_FMA(acc2, H1.y, wD[2]); PK_FMA(acc3, H1.y, wD[3]);

            float a0, a1, a2, a3;
            { F2 u = __builtin_bit_cast(F2, acc0); a0 = u.x + u.y; }
            { F2 u = __builtin_bit_cast(F2, acc1); a1 = u.x + u.y; }
            { F2 u = __builtin_bit_cast(F2, acc2); a2 = u.x + u.y; }
            { F2 u = __builtin_bit_cast(F2, acc3); a3 = u.x + u.y; }

            // cndmask-free butterfly (slot permutation did the routing)
            float c0 = a0 + dpp_get<0xB1>(a1);
            float c1 = a2 + dpp_get<0xB1>(a3);
            float d  = c0 + dpp_get<0x4E>(c1);
            d += dpp_get<0x124>(d);
            d += dpp_get<0x128>(d);

            hv = tanh_pre(d, bias_k);      // bias folded into exp arg

            if (wr) {                      // 16 lanes/wave, contiguous dwords
                hbuf[chain][(q + 1) & 1][jj] = hv;
                *outp = hv;                // store never blocks
            }
            outp += BATCH * HID;

            // h-exchange sync only: lgkmcnt(0) -> ds_write visible; raw
            // s_barrier is opaque to SIInsertWaitcnts (no hidden vmcnt(0)).
            asm volatile("s_waitcnt lgkmcnt(0)" ::: "memory");
            asm volatile("s_barrier" ::: "memory");
        }

        // rotate banks (vmcnt wait lands here, ~4 steps after issue)
#pragma unroll
        for (int i = 0; i < 4; ++i) xa[i] = xn[i];
    }

    // final state (1,B,H): peeled from the loop
    if (wr)
        out[(size_t)SEQ * BATCH * HID + (size_t)b * HID + jj] = hv;
}

extern "C" void kernel_launch(void* const* d_in, const int* in_sizes, int n_in,
                              void* d_out, int out_size, void* d_ws, size_t ws_size,
                              hipStream_t stream) {
    const float* x  = (const float*)d_in[0];
    const float* Wx = (const float*)d_in[1];
    const float* bx = (const float*)d_in[2];
    const float* Wh = (const float*)d_in[3];
    const float* bh = (const float*)d_in[4];
    float* out = (float*)d_out;
    (void)in_sizes; (void)n_in; (void)d_ws; (void)ws_size; (void)out_size;
    rnn_fused<<<dim3(BATCH / 2), dim3(1024), 0, stream>>>(x, Wx, bx, Wh, bh, out);
}